// Round 9
// baseline (114.760 us; speedup 1.0000x reference)
//
#include <hip/hip_runtime.h>
#include <hip/hip_bf16.h>
#include <stdint.h>

#define NNODES 100000
#define DIN    256
#define DOUT   128
#define KNB    16

typedef __attribute__((ext_vector_type(8))) __bf16 bf16x8;
typedef __attribute__((ext_vector_type(4))) float  f32x4;
typedef __attribute__((ext_vector_type(8))) unsigned short u16x8;
typedef __attribute__((ext_vector_type(4))) uint32_t u32x4;

// ---------------------------------------------------------------------------
// Kernel 0: Wt[c][k] = bf16(W[k][c])  (128 x 256 bf16 = 64 KB, L2-resident)
// ---------------------------------------------------------------------------
__global__ __launch_bounds__(256)
void gc_wt(const float* __restrict__ W, unsigned short* __restrict__ Wt)
{
    const int idx = blockIdx.x * 256 + threadIdx.x;   // 0 .. 32767
    const int c = idx >> 8;        // 0..127
    const int k = idx & 255;       // 0..255
    Wt[c * DIN + k] = __builtin_bit_cast(unsigned short, (__bf16)W[k * DOUT + c]);
}

// ---------------------------------------------------------------------------
// Kernel 1: h = relu(feats @ W + b) -> bf16.
// R9: tile shrunk 64->32 rows (grid 3125 EXACT, LDS 16KB, staging regs 32):
// more resident blocks/CU -> inter-block stage/MFMA overlap + finer balance.
// ---------------------------------------------------------------------------
__global__ __launch_bounds__(256, 3)
void gc_linear_relu(const float* __restrict__ feats,
                    const unsigned short* __restrict__ Wt,
                    const float* __restrict__ bias,
                    unsigned short* __restrict__ h)
{
    __shared__ unsigned short As[32 * 256];   // 16 KB bf16, swizzled chunks

    const int t    = threadIdx.x;
    const int lane = t & 63;
    const int wave = t >> 6;                  // 0..3
    const int brow = blockIdx.x * 32;         // 3125*32 = 100000 exact
    const int wcol = wave * 32;
    const int fr   = lane & 15;
    const int kb   = lane >> 4;               // 0..3

    // ---- stage A: issue all 8 global loads first (MLP) ----
    f32x4 sa[4], sb[4];
    int   srow[4], schk[4];
    #pragma unroll
    for (int i = 0; i < 4; ++i) {
        const int id = i * 256 + t;           // 16B-chunk id, 0..1023
        const int r  = id >> 5;               // 0..31
        const int c  = id & 31;               // chunk within row
        const float* ap = feats + (size_t)(brow + r) * DIN + c * 8;
        sa[i] = __builtin_nontemporal_load(reinterpret_cast<const f32x4*>(ap));
        sb[i] = __builtin_nontemporal_load(reinterpret_cast<const f32x4*>(ap + 4));
        srow[i] = r;
        schk[i] = c ^ (r & 15);               // XOR swizzle
    }

    // ---- B fragments from Wt: 16 x 16B L2 loads, independent of staging ----
    bf16x8 bfrag[2][8];
    #pragma unroll
    for (int ct = 0; ct < 2; ++ct) {
        const unsigned short* wp = Wt + (wcol + ct * 16 + fr) * DIN;
        #pragma unroll
        for (int ks = 0; ks < 8; ++ks)
            bfrag[ct][ks] = __builtin_bit_cast(bf16x8,
                *reinterpret_cast<const u16x8*>(wp + ks * 32 + kb * 8));
    }

    #pragma unroll
    for (int i = 0; i < 4; ++i) {
        bf16x8 v;
        v[0] = (__bf16)sa[i][0]; v[1] = (__bf16)sa[i][1];
        v[2] = (__bf16)sa[i][2]; v[3] = (__bf16)sa[i][3];
        v[4] = (__bf16)sb[i][0]; v[5] = (__bf16)sb[i][1];
        v[6] = (__bf16)sb[i][2]; v[7] = (__bf16)sb[i][3];
        *reinterpret_cast<bf16x8*>(&As[srow[i] * 256 + schk[i] * 8]) = v;
    }
    __syncthreads();

    // ---- MFMA: rt in 0..1 (32 rows), ct in 0..1 (wave's 32 cols) ----
    f32x4 acc[2][2];
    #pragma unroll
    for (int rt = 0; rt < 2; ++rt)
        #pragma unroll
        for (int ct = 0; ct < 2; ++ct)
            acc[rt][ct] = (f32x4){0.f, 0.f, 0.f, 0.f};

    #pragma unroll
    for (int rt = 0; rt < 2; ++rt) {
        const int row = rt * 16 + fr;
        #pragma unroll
        for (int ks = 0; ks < 8; ++ks) {
            const int chunk = (ks * 4 + kb) ^ fr;   // row&15 == fr
            const bf16x8 af = *reinterpret_cast<const bf16x8*>(&As[row * 256 + chunk * 8]);
            // swapped operands: D col(lane&15)=feats row, D regs = 4 consecutive h cols
            acc[rt][0] = __builtin_amdgcn_mfma_f32_16x16x32_bf16(bfrag[0][ks], af, acc[rt][0], 0, 0, 0);
            acc[rt][1] = __builtin_amdgcn_mfma_f32_16x16x32_bf16(bfrag[1][ks], af, acc[rt][1], 0, 0, 0);
        }
    }

    // ---- epilogue: h[brow+rt*16+fr][wcol+ct*16+kb*4 + r], r=0..3 ----
    #pragma unroll
    for (int rt = 0; rt < 2; ++rt) {
        const int grow = brow + rt * 16 + fr;     // always < NNODES (exact grid)
        #pragma unroll
        for (int ct = 0; ct < 2; ++ct) {
            const int colb = wcol + ct * 16 + kb * 4;
            union { unsigned short us[4]; uint2 v; } o;
            o.us[0] = __builtin_bit_cast(unsigned short, (__bf16)fmaxf(acc[rt][ct][0] + bias[colb + 0], 0.f));
            o.us[1] = __builtin_bit_cast(unsigned short, (__bf16)fmaxf(acc[rt][ct][1] + bias[colb + 1], 0.f));
            o.us[2] = __builtin_bit_cast(unsigned short, (__bf16)fmaxf(acc[rt][ct][2] + bias[colb + 2], 0.f));
            o.us[3] = __builtin_bit_cast(unsigned short, (__bf16)fmaxf(acc[rt][ct][3] + bias[colb + 3], 0.f));
            *reinterpret_cast<uint2*>(h + (size_t)grow * DOUT + colb) = o.v;
        }
    }
}

// ---------------------------------------------------------------------------
// Kernel 2: out[i][:] = mean_k h[edge[i][k]][:]
// Unchanged forced-MLP structure (R8, verified correct). Now takes a node
// base so it can be launched as two halves (GEMM visibility in top-5 profile).
// ---------------------------------------------------------------------------
__global__ __launch_bounds__(256, 4)
void gc_gather_mean(const int* __restrict__ edge,
                    const unsigned short* __restrict__ h,
                    float* __restrict__ out,
                    int base)
{
    const int t    = threadIdx.x;
    const int grp  = t >> 4;          // node within block (0..15)
    const int c4   = t & 15;          // 16B chunk within row == k index
    const int node = base + blockIdx.x * 16 + grp;
    const int gbase = (t & 63) & 48;  // 16-lane group base within wave

    const int nb_mine = edge[node * KNB + c4];   // lane c4 holds neighbor k=c4

    u32x4 v0, v1, v2, v3, v4, v5, v6, v7, v8, v9, v10, v11, v12, v13, v14, v15;

#define GLOAD(vk, kidx)                                                        \
    {                                                                          \
        const unsigned short* p =                                              \
            h + (size_t)__shfl(nb_mine, gbase | (kidx)) * DOUT + c4 * 8;       \
        asm volatile("global_load_dwordx4 %0, %1, off"                         \
                     : "=v"(vk) : "v"(p));                                     \
    }
    GLOAD(v0, 0)   GLOAD(v1, 1)   GLOAD(v2, 2)   GLOAD(v3, 3)
    GLOAD(v4, 4)   GLOAD(v5, 5)   GLOAD(v6, 6)   GLOAD(v7, 7)
    GLOAD(v8, 8)   GLOAD(v9, 9)   GLOAD(v10, 10) GLOAD(v11, 11)
    GLOAD(v12, 12) GLOAD(v13, 13) GLOAD(v14, 14) GLOAD(v15, 15)
#undef GLOAD

    asm volatile("s_waitcnt vmcnt(0)"
                 : "+v"(v0), "+v"(v1), "+v"(v2),  "+v"(v3),
                   "+v"(v4), "+v"(v5), "+v"(v6),  "+v"(v7),
                   "+v"(v8), "+v"(v9), "+v"(v10), "+v"(v11),
                   "+v"(v12), "+v"(v13), "+v"(v14), "+v"(v15)
                 :
                 : "memory");
    __builtin_amdgcn_sched_barrier(0);

    float s0 = 0.f, s1 = 0.f, s2 = 0.f, s3 = 0.f;
    float s4 = 0.f, s5 = 0.f, s6 = 0.f, s7 = 0.f;

#define ACC(vk)                                                                \
    {                                                                          \
        union { uint32_t u; float f; } lo, hi;                                 \
        lo.u = vk[0] << 16;          s0 += lo.f;                               \
        hi.u = vk[0] & 0xFFFF0000u;  s1 += hi.f;                               \
        lo.u = vk[1] << 16;          s2 += lo.f;                               \
        hi.u = vk[1] & 0xFFFF0000u;  s3 += hi.f;                               \
        lo.u = vk[2] << 16;          s4 += lo.f;                               \
        hi.u = vk[2] & 0xFFFF0000u;  s5 += hi.f;                               \
        lo.u = vk[3] << 16;          s6 += lo.f;                               \
        hi.u = vk[3] & 0xFFFF0000u;  s7 += hi.f;                               \
    }
    ACC(v0)  ACC(v1)  ACC(v2)  ACC(v3)
    ACC(v4)  ACC(v5)  ACC(v6)  ACC(v7)
    ACC(v8)  ACC(v9)  ACC(v10) ACC(v11)
    ACC(v12) ACC(v13) ACC(v14) ACC(v15)
#undef ACC

    float* op = out + (size_t)node * DOUT + c4 * 8;
    f32x4 o0 = {s0 * 0.0625f, s1 * 0.0625f, s2 * 0.0625f, s3 * 0.0625f};
    f32x4 o1 = {s4 * 0.0625f, s5 * 0.0625f, s6 * 0.0625f, s7 * 0.0625f};
    __builtin_nontemporal_store(o0, reinterpret_cast<f32x4*>(op));
    __builtin_nontemporal_store(o1, reinterpret_cast<f32x4*>(op + 4));
}

extern "C" void kernel_launch(void* const* d_in, const int* in_sizes, int n_in,
                              void* d_out, int out_size, void* d_ws, size_t ws_size,
                              hipStream_t stream)
{
    const float* feats = (const float*)d_in[0];
    const int*   edge  = (const int*)d_in[1];
    const float* W     = (const float*)d_in[2];
    const float* bias  = (const float*)d_in[3];
    float* out = (float*)d_out;

    const size_t h_bytes  = (size_t)NNODES * DOUT * sizeof(unsigned short); // 25.6 MB
    const size_t wt_bytes = (size_t)DIN * DOUT * sizeof(unsigned short);    // 64 KB

    unsigned short* h = (unsigned short*)d_ws;
    unsigned short* Wt;
    if (ws_size >= h_bytes + wt_bytes)
        Wt = (unsigned short*)((char*)d_ws + h_bytes);
    else
        Wt = (unsigned short*)d_out;   // gather fully overwrites d_out later

    gc_wt<<<(DIN * DOUT) / 256, 256, 0, stream>>>(W, Wt);

    const int gemm_blocks = NNODES / 32;            // 3125, exact
    gc_linear_relu<<<gemm_blocks, 256, 0, stream>>>(feats, Wt, bias, h);

    // two halves: identical total work; makes GEMM the top dispatch in profile
    const int half_blocks = NNODES / 32;            // 3125 blocks * 16 = 50000 nodes
    gc_gather_mean<<<half_blocks, 256, 0, stream>>>(edge, h, out, 0);
    gc_gather_mean<<<half_blocks, 256, 0, stream>>>(edge, h, out, NNODES / 2);
}

// Round 10
// 99.787 us; speedup vs baseline: 1.1500x; 1.1500x over previous
//
#include <hip/hip_runtime.h>
#include <hip/hip_bf16.h>
#include <stdint.h>

#define NNODES 100000
#define DIN    256
#define DOUT   128
#define KNB    16

typedef __attribute__((ext_vector_type(8))) __bf16 bf16x8;
typedef __attribute__((ext_vector_type(4))) float  f32x4;
typedef __attribute__((ext_vector_type(8))) unsigned short u16x8;
typedef __attribute__((ext_vector_type(4))) uint32_t u32x4;

// ---------------------------------------------------------------------------
// Kernel 0: Wt[c][k] = bf16(W[k][c])  (128 x 256 bf16 = 64 KB, L2-resident)
// ---------------------------------------------------------------------------
__global__ __launch_bounds__(256)
void gc_wt(const float* __restrict__ W, unsigned short* __restrict__ Wt)
{
    const int idx = blockIdx.x * 256 + threadIdx.x;   // 0 .. 32767
    const int c = idx >> 8;        // 0..127
    const int k = idx & 255;       // 0..255
    Wt[c * DIN + k] = __builtin_bit_cast(unsigned short, (__bf16)W[k * DOUT + c]);
}

// ---------------------------------------------------------------------------
// Kernel 1: h = relu(feats @ W + b) -> bf16.  64-row tile (R8 geometry).
// R10: staging loads forced with asm-volatile global_load_dwordx4 + tied
// waitcnt (the R8 gather pattern) so ALL 16 loads are truly in flight —
// R5/R6 proved the scheduler re-rolls source-level MLP phases.
// ---------------------------------------------------------------------------
__global__ __launch_bounds__(256, 2)
void gc_linear_relu(const float* __restrict__ feats,
                    const unsigned short* __restrict__ Wt,
                    const float* __restrict__ bias,
                    unsigned short* __restrict__ h)
{
    __shared__ unsigned short As[64 * 256];   // 32 KB bf16, swizzled chunks

    const int t    = threadIdx.x;
    const int lane = t & 63;
    const int wave = t >> 6;                  // 0..3
    const int brow = blockIdx.x * 64;
    const int wcol = wave * 32;
    const int fr   = lane & 15;
    const int kb   = lane >> 4;               // 0..3

    // ---- stage A: 16 asm-forced loads (pair 2i,2i+1 covers chunk id i) ----
    u32x4 v0, v1, v2, v3, v4, v5, v6, v7, v8, v9, v10, v11, v12, v13, v14, v15;
    int srow[8], schk[8];

#define SLOAD(va, vb, i)                                                       \
    {                                                                          \
        const int id = (i) * 256 + t;       /* 32B-of-f32 chunk id, 0..2047 */ \
        const int r  = id >> 5;             /* 0..63 */                        \
        const int c  = id & 31;             /* chunk within row */             \
        int gr = brow + r; if (gr >= NNODES) gr = NNODES - 1;                  \
        const float* ap = feats + (size_t)gr * DIN + c * 8;                    \
        asm volatile("global_load_dwordx4 %0, %1, off" : "=v"(va) : "v"(ap));  \
        asm volatile("global_load_dwordx4 %0, %1, off" : "=v"(vb) : "v"(ap + 4)); \
        srow[i] = r;                                                           \
        schk[i] = c ^ (r & 15);             /* XOR swizzle */                  \
    }
    SLOAD(v0,  v1,  0) SLOAD(v2,  v3,  1) SLOAD(v4,  v5,  2) SLOAD(v6,  v7,  3)
    SLOAD(v8,  v9,  4) SLOAD(v10, v11, 5) SLOAD(v12, v13, 6) SLOAD(v14, v15, 7)
#undef SLOAD

    // ---- B fragments from Wt: 16 x 16B L2 loads, overlap the HBM wait ----
    bf16x8 bfrag[2][8];
    #pragma unroll
    for (int ct = 0; ct < 2; ++ct) {
        const unsigned short* wp = Wt + (wcol + ct * 16 + fr) * DIN;
        #pragma unroll
        for (int ks = 0; ks < 8; ++ks)
            bfrag[ct][ks] = __builtin_bit_cast(bf16x8,
                *reinterpret_cast<const u16x8*>(wp + ks * 32 + kb * 8));
    }

    // Tie all staging results through the waitcnt (rule #18: consumers must
    // depend on the waitcnt asm itself, or they get hoisted above it).
    asm volatile("s_waitcnt vmcnt(0)"
                 : "+v"(v0), "+v"(v1), "+v"(v2),  "+v"(v3),
                   "+v"(v4), "+v"(v5), "+v"(v6),  "+v"(v7),
                   "+v"(v8), "+v"(v9), "+v"(v10), "+v"(v11),
                   "+v"(v12), "+v"(v13), "+v"(v14), "+v"(v15)
                 :
                 : "memory");
    __builtin_amdgcn_sched_barrier(0);

#define SCVT(va, vb, i)                                                        \
    {                                                                          \
        const f32x4 a = __builtin_bit_cast(f32x4, va);                         \
        const f32x4 b = __builtin_bit_cast(f32x4, vb);                         \
        bf16x8 w;                                                              \
        w[0] = (__bf16)a[0]; w[1] = (__bf16)a[1];                              \
        w[2] = (__bf16)a[2]; w[3] = (__bf16)a[3];                              \
        w[4] = (__bf16)b[0]; w[5] = (__bf16)b[1];                              \
        w[6] = (__bf16)b[2]; w[7] = (__bf16)b[3];                              \
        *reinterpret_cast<bf16x8*>(&As[srow[i] * 256 + schk[i] * 8]) = w;      \
    }
    SCVT(v0,  v1,  0) SCVT(v2,  v3,  1) SCVT(v4,  v5,  2) SCVT(v6,  v7,  3)
    SCVT(v8,  v9,  4) SCVT(v10, v11, 5) SCVT(v12, v13, 6) SCVT(v14, v15, 7)
#undef SCVT
    __syncthreads();

    // ---- MFMA: rt 0..3 (64 rows), ct 0..1 (wave's 32 cols) ----
    f32x4 acc[4][2];
    #pragma unroll
    for (int rt = 0; rt < 4; ++rt)
        #pragma unroll
        for (int ct = 0; ct < 2; ++ct)
            acc[rt][ct] = (f32x4){0.f, 0.f, 0.f, 0.f};

    #pragma unroll
    for (int rt = 0; rt < 4; ++rt) {
        const int row = rt * 16 + fr;
        #pragma unroll
        for (int ks = 0; ks < 8; ++ks) {
            const int chunk = (ks * 4 + kb) ^ fr;   // row&15 == fr
            const bf16x8 af = *reinterpret_cast<const bf16x8*>(&As[row * 256 + chunk * 8]);
            // swapped operands: D col(lane&15)=feats row, D regs = 4 consecutive h cols
            acc[rt][0] = __builtin_amdgcn_mfma_f32_16x16x32_bf16(bfrag[0][ks], af, acc[rt][0], 0, 0, 0);
            acc[rt][1] = __builtin_amdgcn_mfma_f32_16x16x32_bf16(bfrag[1][ks], af, acc[rt][1], 0, 0, 0);
        }
    }

    // ---- epilogue: h[brow+rt*16+fr][wcol+ct*16+kb*4 + r], r=0..3 ----
    #pragma unroll
    for (int rt = 0; rt < 4; ++rt) {
        const int grow = brow + rt * 16 + fr;
        if (grow < NNODES) {
            #pragma unroll
            for (int ct = 0; ct < 2; ++ct) {
                const int colb = wcol + ct * 16 + kb * 4;
                union { unsigned short us[4]; uint2 v; } o;
                o.us[0] = __builtin_bit_cast(unsigned short, (__bf16)fmaxf(acc[rt][ct][0] + bias[colb + 0], 0.f));
                o.us[1] = __builtin_bit_cast(unsigned short, (__bf16)fmaxf(acc[rt][ct][1] + bias[colb + 1], 0.f));
                o.us[2] = __builtin_bit_cast(unsigned short, (__bf16)fmaxf(acc[rt][ct][2] + bias[colb + 2], 0.f));
                o.us[3] = __builtin_bit_cast(unsigned short, (__bf16)fmaxf(acc[rt][ct][3] + bias[colb + 3], 0.f));
                *reinterpret_cast<uint2*>(h + (size_t)grow * DOUT + colb) = o.v;
            }
        }
    }
}

// ---------------------------------------------------------------------------
// Kernel 2: out[i][:] = mean_k h[edge[i][k]][:]  (R8 forced-MLP, single launch)
// ---------------------------------------------------------------------------
__global__ __launch_bounds__(256, 4)
void gc_gather_mean(const int* __restrict__ edge,
                    const unsigned short* __restrict__ h,
                    float* __restrict__ out)
{
    const int t    = threadIdx.x;
    const int grp  = t >> 4;          // node within block (0..15)
    const int c4   = t & 15;          // 16B chunk within row == k index
    const int node = blockIdx.x * 16 + grp;
    const int gbase = (t & 63) & 48;  // 16-lane group base within wave

    const int nb_mine = edge[node * KNB + c4];   // lane c4 holds neighbor k=c4

    u32x4 v0, v1, v2, v3, v4, v5, v6, v7, v8, v9, v10, v11, v12, v13, v14, v15;

#define GLOAD(vk, kidx)                                                        \
    {                                                                          \
        const unsigned short* p =                                              \
            h + (size_t)__shfl(nb_mine, gbase | (kidx)) * DOUT + c4 * 8;       \
        asm volatile("global_load_dwordx4 %0, %1, off"                         \
                     : "=v"(vk) : "v"(p));                                     \
    }
    GLOAD(v0, 0)   GLOAD(v1, 1)   GLOAD(v2, 2)   GLOAD(v3, 3)
    GLOAD(v4, 4)   GLOAD(v5, 5)   GLOAD(v6, 6)   GLOAD(v7, 7)
    GLOAD(v8, 8)   GLOAD(v9, 9)   GLOAD(v10, 10) GLOAD(v11, 11)
    GLOAD(v12, 12) GLOAD(v13, 13) GLOAD(v14, 14) GLOAD(v15, 15)
#undef GLOAD

    asm volatile("s_waitcnt vmcnt(0)"
                 : "+v"(v0), "+v"(v1), "+v"(v2),  "+v"(v3),
                   "+v"(v4), "+v"(v5), "+v"(v6),  "+v"(v7),
                   "+v"(v8), "+v"(v9), "+v"(v10), "+v"(v11),
                   "+v"(v12), "+v"(v13), "+v"(v14), "+v"(v15)
                 :
                 : "memory");
    __builtin_amdgcn_sched_barrier(0);

    float s0 = 0.f, s1 = 0.f, s2 = 0.f, s3 = 0.f;
    float s4 = 0.f, s5 = 0.f, s6 = 0.f, s7 = 0.f;

#define ACC(vk)                                                                \
    {                                                                          \
        union { uint32_t u; float f; } lo, hi;                                 \
        lo.u = vk[0] << 16;          s0 += lo.f;                               \
        hi.u = vk[0] & 0xFFFF0000u;  s1 += hi.f;                               \
        lo.u = vk[1] << 16;          s2 += lo.f;                               \
        hi.u = vk[1] & 0xFFFF0000u;  s3 += hi.f;                               \
        lo.u = vk[2] << 16;          s4 += lo.f;                               \
        hi.u = vk[2] & 0xFFFF0000u;  s5 += hi.f;                               \
        lo.u = vk[3] << 16;          s6 += lo.f;                               \
        hi.u = vk[3] & 0xFFFF0000u;  s7 += hi.f;                               \
    }
    ACC(v0)  ACC(v1)  ACC(v2)  ACC(v3)
    ACC(v4)  ACC(v5)  ACC(v6)  ACC(v7)
    ACC(v8)  ACC(v9)  ACC(v10) ACC(v11)
    ACC(v12) ACC(v13) ACC(v14) ACC(v15)
#undef ACC

    float* op = out + (size_t)node * DOUT + c4 * 8;
    f32x4 o0 = {s0 * 0.0625f, s1 * 0.0625f, s2 * 0.0625f, s3 * 0.0625f};
    f32x4 o1 = {s4 * 0.0625f, s5 * 0.0625f, s6 * 0.0625f, s7 * 0.0625f};
    __builtin_nontemporal_store(o0, reinterpret_cast<f32x4*>(op));
    __builtin_nontemporal_store(o1, reinterpret_cast<f32x4*>(op + 4));
}

extern "C" void kernel_launch(void* const* d_in, const int* in_sizes, int n_in,
                              void* d_out, int out_size, void* d_ws, size_t ws_size,
                              hipStream_t stream)
{
    const float* feats = (const float*)d_in[0];
    const int*   edge  = (const int*)d_in[1];
    const float* W     = (const float*)d_in[2];
    const float* bias  = (const float*)d_in[3];
    float* out = (float*)d_out;

    const size_t h_bytes  = (size_t)NNODES * DOUT * sizeof(unsigned short); // 25.6 MB
    const size_t wt_bytes = (size_t)DIN * DOUT * sizeof(unsigned short);    // 64 KB

    unsigned short* h = (unsigned short*)d_ws;
    unsigned short* Wt;
    if (ws_size >= h_bytes + wt_bytes)
        Wt = (unsigned short*)((char*)d_ws + h_bytes);
    else
        Wt = (unsigned short*)d_out;   // gather fully overwrites d_out later

    gc_wt<<<(DIN * DOUT) / 256, 256, 0, stream>>>(W, Wt);

    const int gemm_blocks = (NNODES + 63) / 64;     // 1563
    gc_linear_relu<<<gemm_blocks, 256, 0, stream>>>(feats, Wt, bias, h);

    const int gat_blocks = NNODES / 16;             // 6250, exact
    gc_gather_mean<<<gat_blocks, 256, 0, stream>>>(edge, h, out);
}

// Round 11
// 97.995 us; speedup vs baseline: 1.1711x; 1.0183x over previous
//
#include <hip/hip_runtime.h>
#include <hip/hip_bf16.h>
#include <stdint.h>

#define NNODES 100000
#define DIN    256
#define DOUT   128
#define KNB    16

typedef __attribute__((ext_vector_type(8))) __bf16 bf16x8;
typedef __attribute__((ext_vector_type(4))) float  f32x4;
typedef __attribute__((ext_vector_type(8))) unsigned short u16x8;
typedef __attribute__((ext_vector_type(4))) uint32_t u32x4;

// ---------------------------------------------------------------------------
// Kernel 0: Wt[c][k] = bf16(W[k][c])  (128 x 256 bf16 = 64 KB, L2-resident)
// ---------------------------------------------------------------------------
__global__ __launch_bounds__(256)
void gc_wt(const float* __restrict__ W, unsigned short* __restrict__ Wt)
{
    const int idx = blockIdx.x * 256 + threadIdx.x;   // 0 .. 32767
    const int c = idx >> 8;        // 0..127
    const int k = idx & 255;       // 0..255
    Wt[c * DIN + k] = __builtin_bit_cast(unsigned short, (__bf16)W[k * DOUT + c]);
}

// ---------------------------------------------------------------------------
// Kernel 1: h = relu(feats @ W + b) -> bf16.  64-row tile, K split 2x128.
// Counted-vmcnt pipeline (T3/T4): ALL staging loads issued up front via asm;
// vmcnt(8) releases half0 while half1 stays in flight ACROSS a raw s_barrier
// (lgkmcnt(0) only — __syncthreads would drain vmcnt(0), the m97 stall).
// ---------------------------------------------------------------------------
__global__ __launch_bounds__(256, 3)
void gc_linear_relu(const float* __restrict__ feats,
                    const unsigned short* __restrict__ Wt,
                    const float* __restrict__ bias,
                    unsigned short* __restrict__ h)
{
    __shared__ unsigned short As[2][64 * 128];   // 2 x 16 KB bf16, swizzled

    const int t    = threadIdx.x;
    const int lane = t & 63;
    const int wave = t >> 6;                  // 0..3
    const int brow = blockIdx.x * 64;
    const int wcol = wave * 32;
    const int fr   = lane & 15;
    const int kb   = lane >> 4;               // 0..3

    // ---- W fragment pointers: bfrag[ct][ks] = Wt[(wcol+ct*16+fr)*256 + ks*32 + kb*8 ..+8]
    const unsigned short* wp0 = Wt + (wcol + fr) * DIN + kb * 8;        // ct=0
    const unsigned short* wp1 = wp0 + 16 * DIN;                          // ct=1

    u32x4 p00, p01, p02, p03, p10, p11, p12, p13;   // W half0 (ks 0..3)
    u32x4 q00, q01, q02, q03, q10, q11, q12, q13;   // W half1 (ks 4..7)
    u32x4 a0, a1, a2, a3, a4, a5, a6, a7;           // A half0 (k 0..127)
    u32x4 b0, b1, b2, b3, b4, b5, b6, b7;           // A half1 (k 128..255)
    int srow[4], schk[4];

    // ---- issue W half0 (8) ----
    asm volatile("global_load_dwordx4 %0, %1, off"            : "=v"(p00) : "v"(wp0));
    asm volatile("global_load_dwordx4 %0, %1, off offset:64"  : "=v"(p01) : "v"(wp0));
    asm volatile("global_load_dwordx4 %0, %1, off offset:128" : "=v"(p02) : "v"(wp0));
    asm volatile("global_load_dwordx4 %0, %1, off offset:192" : "=v"(p03) : "v"(wp0));
    asm volatile("global_load_dwordx4 %0, %1, off"            : "=v"(p10) : "v"(wp1));
    asm volatile("global_load_dwordx4 %0, %1, off offset:64"  : "=v"(p11) : "v"(wp1));
    asm volatile("global_load_dwordx4 %0, %1, off offset:128" : "=v"(p12) : "v"(wp1));
    asm volatile("global_load_dwordx4 %0, %1, off offset:192" : "=v"(p13) : "v"(wp1));

    // ---- issue A half0 (8) then A half1 (8) ----
    // chunk id = i*256 + t; r = id>>4 (0..63); c = id&15 (8-float chunk)
#define SLOADP(va, vb, i, koff, SAVE)                                          \
    {                                                                          \
        const int id = (i) * 256 + t;                                          \
        const int r  = id >> 4;                                                \
        const int c  = id & 15;                                                \
        int gr = brow + r; if (gr >= NNODES) gr = NNODES - 1;                  \
        const float* ap = feats + (size_t)gr * DIN + (koff) + c * 8;           \
        asm volatile("global_load_dwordx4 %0, %1, off" : "=v"(va) : "v"(ap));  \
        asm volatile("global_load_dwordx4 %0, %1, off offset:16" : "=v"(vb) : "v"(ap)); \
        if (SAVE) { srow[i] = r; schk[i] = c ^ (r & 15); }                     \
    }
    SLOADP(a0, a1, 0, 0, 1) SLOADP(a2, a3, 1, 0, 1)
    SLOADP(a4, a5, 2, 0, 1) SLOADP(a6, a7, 3, 0, 1)
    SLOADP(b0, b1, 0, 128, 0) SLOADP(b2, b3, 1, 128, 0)
    SLOADP(b4, b5, 2, 128, 0) SLOADP(b6, b7, 3, 128, 0)
#undef SLOADP

    // ---- wait: W half0 + A half0 done; A half1 (8) may stay in flight ----
    asm volatile("s_waitcnt vmcnt(8)"
                 : "+v"(p00), "+v"(p01), "+v"(p02), "+v"(p03),
                   "+v"(p10), "+v"(p11), "+v"(p12), "+v"(p13),
                   "+v"(a0), "+v"(a1), "+v"(a2), "+v"(a3),
                   "+v"(a4), "+v"(a5), "+v"(a6), "+v"(a7)
                 :: "memory");
    __builtin_amdgcn_sched_barrier(0);

#define SCVT(va, vb, i, HALF)                                                  \
    {                                                                          \
        const f32x4 x = __builtin_bit_cast(f32x4, va);                         \
        const f32x4 y = __builtin_bit_cast(f32x4, vb);                         \
        bf16x8 w;                                                              \
        w[0] = (__bf16)x[0]; w[1] = (__bf16)x[1];                              \
        w[2] = (__bf16)x[2]; w[3] = (__bf16)x[3];                              \
        w[4] = (__bf16)y[0]; w[5] = (__bf16)y[1];                              \
        w[6] = (__bf16)y[2]; w[7] = (__bf16)y[3];                              \
        *reinterpret_cast<bf16x8*>(&As[HALF][srow[i] * 128 + schk[i] * 8]) = w; \
    }
    SCVT(a0, a1, 0, 0) SCVT(a2, a3, 1, 0) SCVT(a4, a5, 2, 0) SCVT(a6, a7, 3, 0)

    // raw barrier: drain LDS writes only, keep A-half1 loads in flight
    asm volatile("s_waitcnt lgkmcnt(0)" ::: "memory");
    __builtin_amdgcn_s_barrier();

    // ---- issue W half1 (8) while computing half0 ----
    asm volatile("global_load_dwordx4 %0, %1, off offset:256" : "=v"(q00) : "v"(wp0));
    asm volatile("global_load_dwordx4 %0, %1, off offset:320" : "=v"(q01) : "v"(wp0));
    asm volatile("global_load_dwordx4 %0, %1, off offset:384" : "=v"(q02) : "v"(wp0));
    asm volatile("global_load_dwordx4 %0, %1, off offset:448" : "=v"(q03) : "v"(wp0));
    asm volatile("global_load_dwordx4 %0, %1, off offset:256" : "=v"(q10) : "v"(wp1));
    asm volatile("global_load_dwordx4 %0, %1, off offset:320" : "=v"(q11) : "v"(wp1));
    asm volatile("global_load_dwordx4 %0, %1, off offset:384" : "=v"(q12) : "v"(wp1));
    asm volatile("global_load_dwordx4 %0, %1, off offset:448" : "=v"(q13) : "v"(wp1));

    f32x4 acc[4][2];
    #pragma unroll
    for (int rt = 0; rt < 4; ++rt)
        #pragma unroll
        for (int ct = 0; ct < 2; ++ct)
            acc[rt][ct] = (f32x4){0.f, 0.f, 0.f, 0.f};

#define MFMA_K(wa, wb, ksl, HALF)                                              \
    {                                                                          \
        _Pragma("unroll")                                                      \
        for (int rt = 0; rt < 4; ++rt) {                                       \
            const int row = rt * 16 + fr;                                      \
            const bf16x8 af = *reinterpret_cast<const bf16x8*>(                \
                &As[HALF][row * 128 + (((ksl) * 4 + kb) ^ fr) * 8]);           \
            acc[rt][0] = __builtin_amdgcn_mfma_f32_16x16x32_bf16(              \
                __builtin_bit_cast(bf16x8, wa), af, acc[rt][0], 0, 0, 0);      \
            acc[rt][1] = __builtin_amdgcn_mfma_f32_16x16x32_bf16(              \
                __builtin_bit_cast(bf16x8, wb), af, acc[rt][1], 0, 0, 0);      \
        }                                                                      \
    }
    // ---- MFMA half0 (A-half1 + W-half1 loads in flight underneath) ----
    MFMA_K(p00, p10, 0, 0) MFMA_K(p01, p11, 1, 0)
    MFMA_K(p02, p12, 2, 0) MFMA_K(p03, p13, 3, 0)

    // ---- wait A half1 (W half1 may remain outstanding) ----
    asm volatile("s_waitcnt vmcnt(8)"
                 : "+v"(b0), "+v"(b1), "+v"(b2), "+v"(b3),
                   "+v"(b4), "+v"(b5), "+v"(b6), "+v"(b7)
                 :: "memory");
    __builtin_amdgcn_sched_barrier(0);

    SCVT(b0, b1, 0, 1) SCVT(b2, b3, 1, 1) SCVT(b4, b5, 2, 1) SCVT(b6, b7, 3, 1)
#undef SCVT

    asm volatile("s_waitcnt lgkmcnt(0)" ::: "memory");
    __builtin_amdgcn_s_barrier();

    // ---- wait W half1, then MFMA half1 ----
    asm volatile("s_waitcnt vmcnt(0)"
                 : "+v"(q00), "+v"(q01), "+v"(q02), "+v"(q03),
                   "+v"(q10), "+v"(q11), "+v"(q12), "+v"(q13)
                 :: "memory");
    __builtin_amdgcn_sched_barrier(0);

    MFMA_K(q00, q10, 0, 1) MFMA_K(q01, q11, 1, 1)
    MFMA_K(q02, q12, 2, 1) MFMA_K(q03, q13, 3, 1)
#undef MFMA_K

    // ---- epilogue: h[brow+rt*16+fr][wcol+ct*16+kb*4 + r], r=0..3 ----
    #pragma unroll
    for (int rt = 0; rt < 4; ++rt) {
        const int grow = brow + rt * 16 + fr;
        if (grow < NNODES) {
            #pragma unroll
            for (int ct = 0; ct < 2; ++ct) {
                const int colb = wcol + ct * 16 + kb * 4;
                union { unsigned short us[4]; uint2 v; } o;
                o.us[0] = __builtin_bit_cast(unsigned short, (__bf16)fmaxf(acc[rt][ct][0] + bias[colb + 0], 0.f));
                o.us[1] = __builtin_bit_cast(unsigned short, (__bf16)fmaxf(acc[rt][ct][1] + bias[colb + 1], 0.f));
                o.us[2] = __builtin_bit_cast(unsigned short, (__bf16)fmaxf(acc[rt][ct][2] + bias[colb + 2], 0.f));
                o.us[3] = __builtin_bit_cast(unsigned short, (__bf16)fmaxf(acc[rt][ct][3] + bias[colb + 3], 0.f));
                *reinterpret_cast<uint2*>(h + (size_t)grow * DOUT + colb) = o.v;
            }
        }
    }
}

// ---------------------------------------------------------------------------
// Kernel 2: out[i][:] = mean_k h[edge[i][k]][:]  (R8 forced-MLP, unchanged —
// at its structural L2-miss/fabric wall: R4 rolled == R8/R10 forced == 59.5us)
// ---------------------------------------------------------------------------
__global__ __launch_bounds__(256, 4)
void gc_gather_mean(const int* __restrict__ edge,
                    const unsigned short* __restrict__ h,
                    float* __restrict__ out)
{
    const int t    = threadIdx.x;
    const int grp  = t >> 4;
    const int c4   = t & 15;
    const int node = blockIdx.x * 16 + grp;
    const int gbase = (t & 63) & 48;

    const int nb_mine = edge[node * KNB + c4];

    u32x4 v0, v1, v2, v3, v4, v5, v6, v7, v8, v9, v10, v11, v12, v13, v14, v15;

#define GLOAD(vk, kidx)                                                        \
    {                                                                          \
        const unsigned short* p =                                              \
            h + (size_t)__shfl(nb_mine, gbase | (kidx)) * DOUT + c4 * 8;       \
        asm volatile("global_load_dwordx4 %0, %1, off"                         \
                     : "=v"(vk) : "v"(p));                                     \
    }
    GLOAD(v0, 0)   GLOAD(v1, 1)   GLOAD(v2, 2)   GLOAD(v3, 3)
    GLOAD(v4, 4)   GLOAD(v5, 5)   GLOAD(v6, 6)   GLOAD(v7, 7)
    GLOAD(v8, 8)   GLOAD(v9, 9)   GLOAD(v10, 10) GLOAD(v11, 11)
    GLOAD(v12, 12) GLOAD(v13, 13) GLOAD(v14, 14) GLOAD(v15, 15)
#undef GLOAD

    asm volatile("s_waitcnt vmcnt(0)"
                 : "+v"(v0), "+v"(v1), "+v"(v2),  "+v"(v3),
                   "+v"(v4), "+v"(v5), "+v"(v6),  "+v"(v7),
                   "+v"(v8), "+v"(v9), "+v"(v10), "+v"(v11),
                   "+v"(v12), "+v"(v13), "+v"(v14), "+v"(v15)
                 :
                 : "memory");
    __builtin_amdgcn_sched_barrier(0);

    float s0 = 0.f, s1 = 0.f, s2 = 0.f, s3 = 0.f;
    float s4 = 0.f, s5 = 0.f, s6 = 0.f, s7 = 0.f;

#define ACC(vk)                                                                \
    {                                                                          \
        union { uint32_t u; float f; } lo, hi;                                 \
        lo.u = vk[0] << 16;          s0 += lo.f;                               \
        hi.u = vk[0] & 0xFFFF0000u;  s1 += hi.f;                               \
        lo.u = vk[1] << 16;          s2 += lo.f;                               \
        hi.u = vk[1] & 0xFFFF0000u;  s3 += hi.f;                               \
        lo.u = vk[2] << 16;          s4 += lo.f;                               \
        hi.u = vk[2] & 0xFFFF0000u;  s5 += hi.f;                               \
        lo.u = vk[3] << 16;          s6 += lo.f;                               \
        hi.u = vk[3] & 0xFFFF0000u;  s7 += hi.f;                               \
    }
    ACC(v0)  ACC(v1)  ACC(v2)  ACC(v3)
    ACC(v4)  ACC(v5)  ACC(v6)  ACC(v7)
    ACC(v8)  ACC(v9)  ACC(v10) ACC(v11)
    ACC(v12) ACC(v13) ACC(v14) ACC(v15)
#undef ACC

    float* op = out + (size_t)node * DOUT + c4 * 8;
    f32x4 o0 = {s0 * 0.0625f, s1 * 0.0625f, s2 * 0.0625f, s3 * 0.0625f};
    f32x4 o1 = {s4 * 0.0625f, s5 * 0.0625f, s6 * 0.0625f, s7 * 0.0625f};
    __builtin_nontemporal_store(o0, reinterpret_cast<f32x4*>(op));
    __builtin_nontemporal_store(o1, reinterpret_cast<f32x4*>(op + 4));
}

extern "C" void kernel_launch(void* const* d_in, const int* in_sizes, int n_in,
                              void* d_out, int out_size, void* d_ws, size_t ws_size,
                              hipStream_t stream)
{
    const float* feats = (const float*)d_in[0];
    const int*   edge  = (const int*)d_in[1];
    const float* W     = (const float*)d_in[2];
    const float* bias  = (const float*)d_in[3];
    float* out = (float*)d_out;

    const size_t h_bytes  = (size_t)NNODES * DOUT * sizeof(unsigned short); // 25.6 MB
    const size_t wt_bytes = (size_t)DIN * DOUT * sizeof(unsigned short);    // 64 KB

    unsigned short* h = (unsigned short*)d_ws;
    unsigned short* Wt;
    if (ws_size >= h_bytes + wt_bytes)
        Wt = (unsigned short*)((char*)d_ws + h_bytes);
    else
        Wt = (unsigned short*)d_out;   // gather fully overwrites d_out later

    gc_wt<<<(DIN * DOUT) / 256, 256, 0, stream>>>(W, Wt);

    const int gemm_blocks = (NNODES + 63) / 64;     // 1563
    gc_linear_relu<<<gemm_blocks, 256, 0, stream>>>(feats, Wt, bias, h);

    const int gat_blocks = NNODES / 16;             // 6250, exact
    gc_gather_mean<<<gat_blocks, 256, 0, stream>>>(edge, h, out);
}

// Round 12
// 96.368 us; speedup vs baseline: 1.1908x; 1.0169x over previous
//
#include <hip/hip_runtime.h>
#include <hip/hip_bf16.h>
#include <stdint.h>

#define NNODES 100000
#define DIN    256
#define DOUT   128
#define KNB    16
#define NTILES 1563          // ceil(100000/64)
#define GBLK   512           // GEMM grid: exactly 2 blocks/CU

typedef __attribute__((ext_vector_type(8))) __bf16 bf16x8;
typedef __attribute__((ext_vector_type(4))) float  f32x4;
typedef __attribute__((ext_vector_type(8))) unsigned short u16x8;
typedef __attribute__((ext_vector_type(4))) uint32_t u32x4;

// ---------------------------------------------------------------------------
// Kernel 0: Wt[c][k] = bf16(W[k][c])  (128 x 256 bf16 = 64 KB, L2-resident)
// ---------------------------------------------------------------------------
__global__ __launch_bounds__(256)
void gc_wt(const float* __restrict__ W, unsigned short* __restrict__ Wt)
{
    const int idx = blockIdx.x * 256 + threadIdx.x;   // 0 .. 32767
    const int c = idx >> 8;        // 0..127
    const int k = idx & 255;       // 0..255
    Wt[c * DIN + k] = __builtin_bit_cast(unsigned short, (__bf16)W[k * DOUT + c]);
}

// ---------------------------------------------------------------------------
// Kernel 1: h = relu(feats @ W + b) -> bf16.
// R12: persistent blocks, 3-4 tiles each, software-pipelined across tiles:
// cvt(i) frees staging regs -> issue A(i+1) -> MFMA(i)+epilogue(i) run with
// tile i+1's 16 HBM loads in flight. W frags loaded once per block. LDS
// double-buffered (2x32KB), one barrier per tile. Only tile0 pays naked
// HBM latency.
// ---------------------------------------------------------------------------
__global__ __launch_bounds__(256, 2)
void gc_linear_relu(const float* __restrict__ feats,
                    const unsigned short* __restrict__ Wt,
                    const float* __restrict__ bias,
                    unsigned short* __restrict__ h)
{
    __shared__ unsigned short As[2][64 * 256];   // 2 x 32 KB bf16, swizzled

    const int t    = threadIdx.x;
    const int lane = t & 63;
    const int wave = t >> 6;                  // 0..3
    const int wcol = wave * 32;
    const int fr   = lane & 15;
    const int kb   = lane >> 4;               // 0..3
    const int bid  = blockIdx.x;

    // contiguous tile range for this block: 3 or 4 tiles
    const int t0 = (int)(((long long)bid     * NTILES) >> 9);
    const int t1 = (int)(((long long)(bid+1) * NTILES) >> 9);

    // per-thread staging geometry (tile-invariant)
    int rr[8], cc[8];
    #pragma unroll
    for (int i = 0; i < 8; ++i) {
        const int id = i * 256 + t;           // 32B-chunk id, 0..2047
        rr[i] = id >> 5;                      // row 0..63
        const int c = id & 31;                // chunk within row
        cc[i] = c ^ (rr[i] & 15);             // swizzled LDS chunk
    }

    u32x4 a0, a1, a2, a3, a4, a5, a6, a7, a8, a9, a10, a11, a12, a13, a14, a15;
    u32x4 p00, p01, p02, p03, p10, p11, p12, p13;   // W ks 0..3 (ct0, ct1)
    u32x4 q00, q01, q02, q03, q10, q11, q12, q13;   // W ks 4..7

#define ISSUE_A(brow)                                                          \
    {                                                                          \
        const float* base = feats;                                             \
        _Pragma("unroll")                                                      \
        for (int i = 0; i < 8; ++i) {                                          \
            int gr = (brow) + rr[i]; if (gr >= NNODES) gr = NNODES - 1;        \
            const float* ap = base + (size_t)gr * DIN + ((i * 256 + t) & 31) * 8; \
            u32x4* va; u32x4* vb;                                              \
            switch (i) {                                                       \
                case 0: va = &a0;  vb = &a1;  break;                           \
                case 1: va = &a2;  vb = &a3;  break;                           \
                case 2: va = &a4;  vb = &a5;  break;                           \
                case 3: va = &a6;  vb = &a7;  break;                           \
                case 4: va = &a8;  vb = &a9;  break;                           \
                case 5: va = &a10; vb = &a11; break;                           \
                case 6: va = &a12; vb = &a13; break;                           \
                default: va = &a14; vb = &a15; break;                          \
            }                                                                  \
            asm volatile("global_load_dwordx4 %0, %1, off" : "=v"(*va) : "v"(ap)); \
            asm volatile("global_load_dwordx4 %0, %1, off offset:16" : "=v"(*vb) : "v"(ap)); \
        }                                                                      \
    }

#define WAIT_A()                                                               \
    asm volatile("s_waitcnt vmcnt(0)"                                          \
                 : "+v"(a0), "+v"(a1), "+v"(a2),  "+v"(a3),                    \
                   "+v"(a4), "+v"(a5), "+v"(a6),  "+v"(a7),                    \
                   "+v"(a8), "+v"(a9), "+v"(a10), "+v"(a11),                   \
                   "+v"(a12), "+v"(a13), "+v"(a14), "+v"(a15)                  \
                 :: "memory");                                                 \
    __builtin_amdgcn_sched_barrier(0);

    // ---- prologue: issue A(t0) then W (W is L2-fast, drained together) ----
    ISSUE_A(t0 * 64)

    const unsigned short* wp0 = Wt + (wcol + fr) * DIN + kb * 8;   // ct=0
    const unsigned short* wp1 = wp0 + 16 * DIN;                    // ct=1
    asm volatile("global_load_dwordx4 %0, %1, off"            : "=v"(p00) : "v"(wp0));
    asm volatile("global_load_dwordx4 %0, %1, off offset:64"  : "=v"(p01) : "v"(wp0));
    asm volatile("global_load_dwordx4 %0, %1, off offset:128" : "=v"(p02) : "v"(wp0));
    asm volatile("global_load_dwordx4 %0, %1, off offset:192" : "=v"(p03) : "v"(wp0));
    asm volatile("global_load_dwordx4 %0, %1, off"            : "=v"(p10) : "v"(wp1));
    asm volatile("global_load_dwordx4 %0, %1, off offset:64"  : "=v"(p11) : "v"(wp1));
    asm volatile("global_load_dwordx4 %0, %1, off offset:128" : "=v"(p12) : "v"(wp1));
    asm volatile("global_load_dwordx4 %0, %1, off offset:192" : "=v"(p13) : "v"(wp1));
    asm volatile("global_load_dwordx4 %0, %1, off offset:256" : "=v"(q00) : "v"(wp0));
    asm volatile("global_load_dwordx4 %0, %1, off offset:320" : "=v"(q01) : "v"(wp0));
    asm volatile("global_load_dwordx4 %0, %1, off offset:384" : "=v"(q02) : "v"(wp0));
    asm volatile("global_load_dwordx4 %0, %1, off offset:448" : "=v"(q03) : "v"(wp0));
    asm volatile("global_load_dwordx4 %0, %1, off offset:256" : "=v"(q10) : "v"(wp1));
    asm volatile("global_load_dwordx4 %0, %1, off offset:320" : "=v"(q11) : "v"(wp1));
    asm volatile("global_load_dwordx4 %0, %1, off offset:384" : "=v"(q12) : "v"(wp1));
    asm volatile("global_load_dwordx4 %0, %1, off offset:448" : "=v"(q13) : "v"(wp1));

    // drain everything once (W + A(t0))
    asm volatile("s_waitcnt vmcnt(0)"
                 : "+v"(a0), "+v"(a1), "+v"(a2),  "+v"(a3),
                   "+v"(a4), "+v"(a5), "+v"(a6),  "+v"(a7),
                   "+v"(a8), "+v"(a9), "+v"(a10), "+v"(a11),
                   "+v"(a12), "+v"(a13), "+v"(a14), "+v"(a15),
                   "+v"(p00), "+v"(p01), "+v"(p02), "+v"(p03),
                   "+v"(p10), "+v"(p11), "+v"(p12), "+v"(p13),
                   "+v"(q00), "+v"(q01), "+v"(q02), "+v"(q03),
                   "+v"(q10), "+v"(q11), "+v"(q12), "+v"(q13)
                 :: "memory");
    __builtin_amdgcn_sched_barrier(0);

    int buf = 0;
    for (int tile = t0; tile < t1; ++tile) {
        const int brow = tile * 64;
        const bool pf = (tile + 1 < t1);

        // ---- cvt staged regs -> LDS[buf] (frees staging regs) ----
#define SCVT(va, vb, i)                                                        \
        {                                                                      \
            const f32x4 x = __builtin_bit_cast(f32x4, va);                     \
            const f32x4 y = __builtin_bit_cast(f32x4, vb);                     \
            bf16x8 w;                                                          \
            w[0] = (__bf16)x[0]; w[1] = (__bf16)x[1];                          \
            w[2] = (__bf16)x[2]; w[3] = (__bf16)x[3];                          \
            w[4] = (__bf16)y[0]; w[5] = (__bf16)y[1];                          \
            w[6] = (__bf16)y[2]; w[7] = (__bf16)y[3];                          \
            *reinterpret_cast<bf16x8*>(&As[buf][rr[i] * 256 + cc[i] * 8]) = w; \
        }
        SCVT(a0,  a1,  0) SCVT(a2,  a3,  1) SCVT(a4,  a5,  2) SCVT(a6,  a7,  3)
        SCVT(a8,  a9,  4) SCVT(a10, a11, 5) SCVT(a12, a13, 6) SCVT(a14, a15, 7)
#undef SCVT

        asm volatile("s_waitcnt lgkmcnt(0)" ::: "memory");
        __builtin_amdgcn_s_barrier();

        // ---- prefetch next tile's A into the (now free) staging regs ----
        if (pf) ISSUE_A(brow + 64)

        // ---- MFMA from LDS[buf] ----
        f32x4 acc[4][2];
        #pragma unroll
        for (int rt = 0; rt < 4; ++rt) {
            acc[rt][0] = (f32x4){0.f, 0.f, 0.f, 0.f};
            acc[rt][1] = (f32x4){0.f, 0.f, 0.f, 0.f};
        }

#define MFMA_K(wa, wb, ksl)                                                    \
        {                                                                      \
            _Pragma("unroll")                                                  \
            for (int rt = 0; rt < 4; ++rt) {                                   \
                const int row = rt * 16 + fr;                                  \
                const bf16x8 af = *reinterpret_cast<const bf16x8*>(            \
                    &As[buf][row * 256 + (((ksl) * 4 + kb) ^ fr) * 8]);        \
                acc[rt][0] = __builtin_amdgcn_mfma_f32_16x16x32_bf16(          \
                    __builtin_bit_cast(bf16x8, wa), af, acc[rt][0], 0, 0, 0);  \
                acc[rt][1] = __builtin_amdgcn_mfma_f32_16x16x32_bf16(          \
                    __builtin_bit_cast(bf16x8, wb), af, acc[rt][1], 0, 0, 0);  \
            }                                                                  \
        }
        MFMA_K(p00, p10, 0) MFMA_K(p01, p11, 1)
        MFMA_K(p02, p12, 2) MFMA_K(p03, p13, 3)
        MFMA_K(q00, q10, 4) MFMA_K(q01, q11, 5)
        MFMA_K(q02, q12, 6) MFMA_K(q03, q13, 7)
#undef MFMA_K

        // ---- epilogue: h[brow+rt*16+fr][wcol+ct*16+kb*4 + r] ----
        #pragma unroll
        for (int rt = 0; rt < 4; ++rt) {
            const int grow = brow + rt * 16 + fr;
            if (grow < NNODES) {
                #pragma unroll
                for (int ct = 0; ct < 2; ++ct) {
                    const int colb = wcol + ct * 16 + kb * 4;
                    union { unsigned short us[4]; uint2 v; } o;
                    o.us[0] = __builtin_bit_cast(unsigned short, (__bf16)fmaxf(acc[rt][ct][0] + bias[colb + 0], 0.f));
                    o.us[1] = __builtin_bit_cast(unsigned short, (__bf16)fmaxf(acc[rt][ct][1] + bias[colb + 1], 0.f));
                    o.us[2] = __builtin_bit_cast(unsigned short, (__bf16)fmaxf(acc[rt][ct][2] + bias[colb + 2], 0.f));
                    o.us[3] = __builtin_bit_cast(unsigned short, (__bf16)fmaxf(acc[rt][ct][3] + bias[colb + 3], 0.f));
                    *reinterpret_cast<uint2*>(h + (size_t)grow * DOUT + colb) = o.v;
                }
            }
        }

        // ---- wait for prefetched tile before consuming it next iter ----
        if (pf) WAIT_A()
        buf ^= 1;
    }
#undef ISSUE_A
#undef WAIT_A
}

// ---------------------------------------------------------------------------
// Kernel 2: out[i][:] = mean_k h[edge[i][k]][:]  (R8 forced-MLP — at its
// structural wall: FETCH 173MB == XCD replication floor; 59.3us flat)
// ---------------------------------------------------------------------------
__global__ __launch_bounds__(256, 4)
void gc_gather_mean(const int* __restrict__ edge,
                    const unsigned short* __restrict__ h,
                    float* __restrict__ out)
{
    const int t    = threadIdx.x;
    const int grp  = t >> 4;
    const int c4   = t & 15;
    const int node = blockIdx.x * 16 + grp;
    const int gbase = (t & 63) & 48;

    const int nb_mine = edge[node * KNB + c4];

    u32x4 v0, v1, v2, v3, v4, v5, v6, v7, v8, v9, v10, v11, v12, v13, v14, v15;

#define GLOAD(vk, kidx)                                                        \
    {                                                                          \
        const unsigned short* p =                                              \
            h + (size_t)__shfl(nb_mine, gbase | (kidx)) * DOUT + c4 * 8;       \
        asm volatile("global_load_dwordx4 %0, %1, off"                         \
                     : "=v"(vk) : "v"(p));                                     \
    }
    GLOAD(v0, 0)   GLOAD(v1, 1)   GLOAD(v2, 2)   GLOAD(v3, 3)
    GLOAD(v4, 4)   GLOAD(v5, 5)   GLOAD(v6, 6)   GLOAD(v7, 7)
    GLOAD(v8, 8)   GLOAD(v9, 9)   GLOAD(v10, 10) GLOAD(v11, 11)
    GLOAD(v12, 12) GLOAD(v13, 13) GLOAD(v14, 14) GLOAD(v15, 15)
#undef GLOAD

    asm volatile("s_waitcnt vmcnt(0)"
                 : "+v"(v0), "+v"(v1), "+v"(v2),  "+v"(v3),
                   "+v"(v4), "+v"(v5), "+v"(v6),  "+v"(v7),
                   "+v"(v8), "+v"(v9), "+v"(v10), "+v"(v11),
                   "+v"(v12), "+v"(v13), "+v"(v14), "+v"(v15)
                 :
                 : "memory");
    __builtin_amdgcn_sched_barrier(0);

    float s0 = 0.f, s1 = 0.f, s2 = 0.f, s3 = 0.f;
    float s4 = 0.f, s5 = 0.f, s6 = 0.f, s7 = 0.f;

#define ACC(vk)                                                                \
    {                                                                          \
        union { uint32_t u; float f; } lo, hi;                                 \
        lo.u = vk[0] << 16;          s0 += lo.f;                               \
        hi.u = vk[0] & 0xFFFF0000u;  s1 += hi.f;                               \
        lo.u = vk[1] << 16;          s2 += lo.f;                               \
        hi.u = vk[1] & 0xFFFF0000u;  s3 += hi.f;                               \
        lo.u = vk[2] << 16;          s4 += lo.f;                               \
        hi.u = vk[2] & 0xFFFF0000u;  s5 += hi.f;                               \
        lo.u = vk[3] << 16;          s6 += lo.f;                               \
        hi.u = vk[3] & 0xFFFF0000u;  s7 += hi.f;                               \
    }
    ACC(v0)  ACC(v1)  ACC(v2)  ACC(v3)
    ACC(v4)  ACC(v5)  ACC(v6)  ACC(v7)
    ACC(v8)  ACC(v9)  ACC(v10) ACC(v11)
    ACC(v12) ACC(v13) ACC(v14) ACC(v15)
#undef ACC

    float* op = out + (size_t)node * DOUT + c4 * 8;
    f32x4 o0 = {s0 * 0.0625f, s1 * 0.0625f, s2 * 0.0625f, s3 * 0.0625f};
    f32x4 o1 = {s4 * 0.0625f, s5 * 0.0625f, s6 * 0.0625f, s7 * 0.0625f};
    __builtin_nontemporal_store(o0, reinterpret_cast<f32x4*>(op));
    __builtin_nontemporal_store(o1, reinterpret_cast<f32x4*>(op + 4));
}

extern "C" void kernel_launch(void* const* d_in, const int* in_sizes, int n_in,
                              void* d_out, int out_size, void* d_ws, size_t ws_size,
                              hipStream_t stream)
{
    const float* feats = (const float*)d_in[0];
    const int*   edge  = (const int*)d_in[1];
    const float* W     = (const float*)d_in[2];
    const float* bias  = (const float*)d_in[3];
    float* out = (float*)d_out;

    const size_t h_bytes  = (size_t)NNODES * DOUT * sizeof(unsigned short); // 25.6 MB
    const size_t wt_bytes = (size_t)DIN * DOUT * sizeof(unsigned short);    // 64 KB

    unsigned short* h = (unsigned short*)d_ws;
    unsigned short* Wt;
    if (ws_size >= h_bytes + wt_bytes)
        Wt = (unsigned short*)((char*)d_ws + h_bytes);
    else
        Wt = (unsigned short*)d_out;   // gather fully overwrites d_out later

    gc_wt<<<(DIN * DOUT) / 256, 256, 0, stream>>>(W, Wt);

    gc_linear_relu<<<GBLK, 256, 0, stream>>>(feats, Wt, bias, h);

    const int gat_blocks = NNODES / 16;             // 6250, exact
    gc_gather_mean<<<gat_blocks, 256, 0, stream>>>(edge, h, out);
}